// Round 1
// baseline (248.547 us; speedup 1.0000x reference)
//
#include <hip/hip_runtime.h>
#include <math.h>

#define NPTS 6890
#define BATCH 1024

// ---------------------------------------------------------------------------
// Kernel 1: per-batch reduction of 16 raw sums:
//   [0..2]  sum pred_i      [3..5] sum gt_i     [6] sum |pred|^2
//   [7..15] sum pred_i*gt_j (row-major i,j)
// One block (256 thr) per batch; wave shuffle reduce then LDS cross-wave.
// ---------------------------------------------------------------------------
__global__ __launch_bounds__(256) void reduce_kernel(
    const float* __restrict__ pred, const float* __restrict__ gt,
    float* __restrict__ sums) {
  const int b = blockIdx.x;
  const float* __restrict__ p = pred + (size_t)b * (NPTS * 3);
  const float* __restrict__ g = gt   + (size_t)b * (NPTS * 3);

  float acc[16];
#pragma unroll
  for (int i = 0; i < 16; ++i) acc[i] = 0.f;

  for (int n = threadIdx.x; n < NPTS; n += 256) {
    const int j = 3 * n;
    const float p0 = p[j], p1 = p[j + 1], p2 = p[j + 2];
    const float g0 = g[j], g1 = g[j + 1], g2 = g[j + 2];
    acc[0] += p0;  acc[1] += p1;  acc[2] += p2;
    acc[3] += g0;  acc[4] += g1;  acc[5] += g2;
    acc[6] += p0 * p0 + p1 * p1 + p2 * p2;
    acc[7]  += p0 * g0;  acc[8]  += p0 * g1;  acc[9]  += p0 * g2;
    acc[10] += p1 * g0;  acc[11] += p1 * g1;  acc[12] += p1 * g2;
    acc[13] += p2 * g0;  acc[14] += p2 * g1;  acc[15] += p2 * g2;
  }

  // wave64 butterfly reduce each of the 16 values
#pragma unroll
  for (int i = 0; i < 16; ++i) {
#pragma unroll
    for (int off = 32; off > 0; off >>= 1)
      acc[i] += __shfl_down(acc[i], off, 64);
  }

  __shared__ float red[4][16];
  const int wave = threadIdx.x >> 6;
  const int lane = threadIdx.x & 63;
  if (lane == 0) {
#pragma unroll
    for (int i = 0; i < 16; ++i) red[wave][i] = acc[i];
  }
  __syncthreads();
  if (threadIdx.x < 16) {
    const int i = threadIdx.x;
    sums[b * 16 + i] = red[0][i] + red[1][i] + red[2][i] + red[3][i];
  }
}

// ---------------------------------------------------------------------------
// Kernel 2: per-batch solve (fp64). One thread per batch.
//   K = cross-cov + EPS; A = K^T K; Jacobi eigendecomp -> V, s^2.
//   sign = sign(det K)  (== sign(det(U Vh)) since s_i >= 0)
//   R = V diag(z_i/s_i) V^T K^T  with z = (1,1,sign) on sorted (desc) s.
//   trace(RK) = s1 + s2 + sign*s3; scale = trace/var1; t = mu2 - scale*R*mu1.
// Emits params[b*12]: M = scale*R (9, row-major), t (3).
// ---------------------------------------------------------------------------
__global__ void solve_kernel(const float* __restrict__ sums,
                             float* __restrict__ params) {
  const int b = blockIdx.x * blockDim.x + threadIdx.x;
  if (b >= BATCH) return;
  const float* s = sums + b * 16;
  const double Ninv = 1.0 / (double)NPTS;

  double sp[3] = {s[0], s[1], s[2]};
  double sg[3] = {s[3], s[4], s[5]};
  double mu1[3], mu2[3];
#pragma unroll
  for (int i = 0; i < 3; ++i) { mu1[i] = sp[i] * Ninv; mu2[i] = sg[i] * Ninv; }
  const double var1 =
      (double)s[6] - (sp[0] * sp[0] + sp[1] * sp[1] + sp[2] * sp[2]) * Ninv;

  double K[3][3];
#pragma unroll
  for (int i = 0; i < 3; ++i)
#pragma unroll
    for (int j = 0; j < 3; ++j)
      K[i][j] = (double)s[7 + 3 * i + j] - sp[i] * sg[j] * Ninv + 1e-8;

  // A = K^T K (symmetric PSD)
  double A[3][3];
#pragma unroll
  for (int i = 0; i < 3; ++i)
#pragma unroll
    for (int j = 0; j < 3; ++j)
      A[i][j] = K[0][i] * K[0][j] + K[1][i] * K[1][j] + K[2][i] * K[2][j];

  double V[3][3] = {{1, 0, 0}, {0, 1, 0}, {0, 0, 1}};
  for (int sweep = 0; sweep < 30; ++sweep) {
    const double off = A[0][1] * A[0][1] + A[0][2] * A[0][2] + A[1][2] * A[1][2];
    const double nrm = A[0][0] + A[1][1] + A[2][2];
    if (off <= 1e-30 * nrm * nrm) break;
    for (int pq = 0; pq < 3; ++pq) {
      const int p = (pq == 2) ? 1 : 0;
      const int q = (pq == 0) ? 1 : 2;
      const double apq = A[p][q];
      if (apq == 0.0) continue;
      const double theta = (A[q][q] - A[p][p]) / (2.0 * apq);
      const double tt =
          ((theta >= 0.0) ? 1.0 : -1.0) / (fabs(theta) + sqrt(theta * theta + 1.0));
      const double c = 1.0 / sqrt(tt * tt + 1.0);
      const double sn = tt * c;
      const double app = A[p][p], aqq = A[q][q];
      A[p][p] = app - tt * apq;
      A[q][q] = aqq + tt * apq;
      A[p][q] = 0.0; A[q][p] = 0.0;
      const int r = 3 - p - q;
      const double arp = A[r][p], arq = A[r][q];
      A[r][p] = c * arp - sn * arq; A[p][r] = A[r][p];
      A[r][q] = sn * arp + c * arq; A[q][r] = A[r][q];
#pragma unroll
      for (int k = 0; k < 3; ++k) {
        const double vkp = V[k][p], vkq = V[k][q];
        V[k][p] = c * vkp - sn * vkq;
        V[k][q] = sn * vkp + c * vkq;
      }
    }
  }

  double w[3] = {A[0][0], A[1][1], A[2][2]};
  int i0 = 0, i1 = 1, i2 = 2, tmp;
  if (w[i0] < w[i1]) { tmp = i0; i0 = i1; i1 = tmp; }
  if (w[i0] < w[i2]) { tmp = i0; i0 = i2; i2 = tmp; }
  if (w[i1] < w[i2]) { tmp = i1; i1 = i2; i2 = tmp; }
  const double sv0 = sqrt(fmax(w[i0], 0.0));
  const double sv1 = sqrt(fmax(w[i1], 0.0));
  const double sv2 = sqrt(fmax(w[i2], 0.0));

  const double detK =
      K[0][0] * (K[1][1] * K[2][2] - K[1][2] * K[2][1]) -
      K[0][1] * (K[1][0] * K[2][2] - K[1][2] * K[2][0]) +
      K[0][2] * (K[1][0] * K[2][1] - K[1][1] * K[2][0]);
  const double sgn = (detK > 0.0) ? 1.0 : ((detK < 0.0) ? -1.0 : 0.0);

  const double floor0 = sv0 * 1e-12 + 1e-300;  // keep R sane if K near-singular
  const double z0 = 1.0 / fmax(sv0, floor0);
  const double z1 = 1.0 / fmax(sv1, floor0);
  const double z2 = sgn / fmax(sv2, floor0);

  double W[3][3];
#pragma unroll
  for (int a = 0; a < 3; ++a)
#pragma unroll
    for (int c = 0; c < 3; ++c)
      W[a][c] = V[a][i0] * V[c][i0] * z0 + V[a][i1] * V[c][i1] * z1 +
                V[a][i2] * V[c][i2] * z2;

  double R[3][3];
#pragma unroll
  for (int a = 0; a < 3; ++a)
#pragma unroll
    for (int c = 0; c < 3; ++c)
      R[a][c] = W[a][0] * K[c][0] + W[a][1] * K[c][1] + W[a][2] * K[c][2];

  const double trace = sv0 + sv1 + sgn * sv2;
  const double scale = trace / var1;

  float* pr = params + b * 12;
#pragma unroll
  for (int a = 0; a < 3; ++a) {
#pragma unroll
    for (int c = 0; c < 3; ++c) pr[3 * a + c] = (float)(scale * R[a][c]);
    pr[9 + a] = (float)(mu2[a] - scale * (R[a][0] * mu1[0] + R[a][1] * mu1[1] +
                                          R[a][2] * mu1[2]));
  }
}

// ---------------------------------------------------------------------------
// Kernel 3: apply |M p + t - g| per point.
// ---------------------------------------------------------------------------
__global__ __launch_bounds__(256) void apply_kernel(
    const float* __restrict__ pred, const float* __restrict__ gt,
    const float* __restrict__ params, float* __restrict__ out) {
  const int b = blockIdx.y;
  const int n = blockIdx.x * blockDim.x + threadIdx.x;
  const float* pr = params + b * 12;
  const float m00 = pr[0], m01 = pr[1], m02 = pr[2];
  const float m10 = pr[3], m11 = pr[4], m12 = pr[5];
  const float m20 = pr[6], m21 = pr[7], m22 = pr[8];
  const float t0 = pr[9], t1 = pr[10], t2 = pr[11];
  if (n < NPTS) {
    const size_t base = ((size_t)b * NPTS + n) * 3;
    const float p0 = pred[base], p1 = pred[base + 1], p2 = pred[base + 2];
    const float g0 = gt[base], g1 = gt[base + 1], g2 = gt[base + 2];
    out[base]     = fabsf(m00 * p0 + m01 * p1 + m02 * p2 + t0 - g0);
    out[base + 1] = fabsf(m10 * p0 + m11 * p1 + m12 * p2 + t1 - g1);
    out[base + 2] = fabsf(m20 * p0 + m21 * p1 + m22 * p2 + t2 - g2);
  }
}

extern "C" void kernel_launch(void* const* d_in, const int* in_sizes, int n_in,
                              void* d_out, int out_size, void* d_ws, size_t ws_size,
                              hipStream_t stream) {
  const float* pred = (const float*)d_in[0];
  const float* gt   = (const float*)d_in[1];
  float* out = (float*)d_out;
  float* sums   = (float*)d_ws;            // BATCH*16 floats
  float* params = sums + BATCH * 16;       // BATCH*12 floats

  hipLaunchKernelGGL(reduce_kernel, dim3(BATCH), dim3(256), 0, stream,
                     pred, gt, sums);
  hipLaunchKernelGGL(solve_kernel, dim3((BATCH + 255) / 256), dim3(256), 0,
                     stream, sums, params);
  hipLaunchKernelGGL(apply_kernel, dim3((NPTS + 255) / 256, BATCH), dim3(256),
                     0, stream, pred, gt, params, out);
}

// Round 2
// 246.345 us; speedup vs baseline: 1.0089x; 1.0089x over previous
//
#include <hip/hip_runtime.h>
#include <math.h>

#define NPTS 6890
#define BATCH 1024
#define FLOATS_PER_BATCH (NPTS * 3)   // 20670; mod 4 == 2
#define NGROUPS 1722                  // groups of 4 points covered by float4s

// Accumulate one point-pair into the 16 sums.
__device__ __forceinline__ void accum(float* acc, float p0, float p1, float p2,
                                      float g0, float g1, float g2) {
  acc[0] += p0;  acc[1] += p1;  acc[2] += p2;
  acc[3] += g0;  acc[4] += g1;  acc[5] += g2;
  acc[6] += p0 * p0 + p1 * p1 + p2 * p2;
  acc[7]  += p0 * g0;  acc[8]  += p0 * g1;  acc[9]  += p0 * g2;
  acc[10] += p1 * g0;  acc[11] += p1 * g1;  acc[12] += p1 * g2;
  acc[13] += p2 * g0;  acc[14] += p2 * g1;  acc[15] += p2 * g2;
}

// ---------------------------------------------------------------------------
// Kernel 1: per-batch reduction of 16 raw sums (float4-vectorized).
//   [0..2] sum p  [3..5] sum g  [6] sum|p|^2  [7..15] sum p_i*g_j
// Batch base b*20670 is 16B-aligned only for even b; odd b skips 2 points
// (6 floats) to realign. The 2 leftover points (head for odd b, tail for
// even b) are handled scalar by threads 0/1.
// ---------------------------------------------------------------------------
__global__ __launch_bounds__(256) void reduce_kernel(
    const float* __restrict__ pred, const float* __restrict__ gt,
    float* __restrict__ sums) {
  const int b = blockIdx.x;
  const size_t ofs0 = (size_t)b * FLOATS_PER_BATCH;
  const int skip = (b & 1) ? 2 : 0;                  // points skipped at head
  const size_t ofs = ofs0 + (size_t)skip * 3;        // 16B-aligned float idx
  const float4* __restrict__ p4 = (const float4*)(pred + ofs);
  const float4* __restrict__ g4 = (const float4*)(gt + ofs);

  float acc[16];
#pragma unroll
  for (int i = 0; i < 16; ++i) acc[i] = 0.f;

  for (int gi = threadIdx.x; gi < NGROUPS; gi += 256) {
    const float4 a0 = p4[3 * gi], a1 = p4[3 * gi + 1], a2 = p4[3 * gi + 2];
    const float4 c0 = g4[3 * gi], c1 = g4[3 * gi + 1], c2 = g4[3 * gi + 2];
    accum(acc, a0.x, a0.y, a0.z, c0.x, c0.y, c0.z);
    accum(acc, a0.w, a1.x, a1.y, c0.w, c1.x, c1.y);
    accum(acc, a1.z, a1.w, a2.x, c1.z, c1.w, c2.x);
    accum(acc, a2.y, a2.z, a2.w, c2.y, c2.z, c2.w);
  }

  // 2 leftover scalar points per batch
  if (threadIdx.x < 2) {
    const int n = skip ? (int)threadIdx.x : (NPTS - 2 + (int)threadIdx.x);
    const float* pp = pred + ofs0 + 3 * n;
    const float* gg = gt + ofs0 + 3 * n;
    accum(acc, pp[0], pp[1], pp[2], gg[0], gg[1], gg[2]);
  }

  // wave64 butterfly reduce each of the 16 values
#pragma unroll
  for (int i = 0; i < 16; ++i) {
#pragma unroll
    for (int off = 32; off > 0; off >>= 1)
      acc[i] += __shfl_down(acc[i], off, 64);
  }

  __shared__ float red[4][16];
  const int wave = threadIdx.x >> 6;
  const int lane = threadIdx.x & 63;
  if (lane == 0) {
#pragma unroll
    for (int i = 0; i < 16; ++i) red[wave][i] = acc[i];
  }
  __syncthreads();
  if (threadIdx.x < 16) {
    const int i = threadIdx.x;
    sums[b * 16 + i] = red[0][i] + red[1][i] + red[2][i] + red[3][i];
  }
}

// ---------------------------------------------------------------------------
// Kernel 2: per-batch solve (fp64). One thread per batch. (unchanged R1)
// ---------------------------------------------------------------------------
__global__ void solve_kernel(const float* __restrict__ sums,
                             float* __restrict__ params) {
  const int b = blockIdx.x * blockDim.x + threadIdx.x;
  if (b >= BATCH) return;
  const float* s = sums + b * 16;
  const double Ninv = 1.0 / (double)NPTS;

  double sp[3] = {s[0], s[1], s[2]};
  double sg[3] = {s[3], s[4], s[5]};
  double mu1[3], mu2[3];
#pragma unroll
  for (int i = 0; i < 3; ++i) { mu1[i] = sp[i] * Ninv; mu2[i] = sg[i] * Ninv; }
  const double var1 =
      (double)s[6] - (sp[0] * sp[0] + sp[1] * sp[1] + sp[2] * sp[2]) * Ninv;

  double K[3][3];
#pragma unroll
  for (int i = 0; i < 3; ++i)
#pragma unroll
    for (int j = 0; j < 3; ++j)
      K[i][j] = (double)s[7 + 3 * i + j] - sp[i] * sg[j] * Ninv + 1e-8;

  double A[3][3];
#pragma unroll
  for (int i = 0; i < 3; ++i)
#pragma unroll
    for (int j = 0; j < 3; ++j)
      A[i][j] = K[0][i] * K[0][j] + K[1][i] * K[1][j] + K[2][i] * K[2][j];

  double V[3][3] = {{1, 0, 0}, {0, 1, 0}, {0, 0, 1}};
  for (int sweep = 0; sweep < 30; ++sweep) {
    const double off = A[0][1] * A[0][1] + A[0][2] * A[0][2] + A[1][2] * A[1][2];
    const double nrm = A[0][0] + A[1][1] + A[2][2];
    if (off <= 1e-30 * nrm * nrm) break;
    for (int pq = 0; pq < 3; ++pq) {
      const int p = (pq == 2) ? 1 : 0;
      const int q = (pq == 0) ? 1 : 2;
      const double apq = A[p][q];
      if (apq == 0.0) continue;
      const double theta = (A[q][q] - A[p][p]) / (2.0 * apq);
      const double tt =
          ((theta >= 0.0) ? 1.0 : -1.0) / (fabs(theta) + sqrt(theta * theta + 1.0));
      const double c = 1.0 / sqrt(tt * tt + 1.0);
      const double sn = tt * c;
      const double app = A[p][p], aqq = A[q][q];
      A[p][p] = app - tt * apq;
      A[q][q] = aqq + tt * apq;
      A[p][q] = 0.0; A[q][p] = 0.0;
      const int r = 3 - p - q;
      const double arp = A[r][p], arq = A[r][q];
      A[r][p] = c * arp - sn * arq; A[p][r] = A[r][p];
      A[r][q] = sn * arp + c * arq; A[q][r] = A[r][q];
#pragma unroll
      for (int k = 0; k < 3; ++k) {
        const double vkp = V[k][p], vkq = V[k][q];
        V[k][p] = c * vkp - sn * vkq;
        V[k][q] = sn * vkp + c * vkq;
      }
    }
  }

  double w[3] = {A[0][0], A[1][1], A[2][2]};
  int i0 = 0, i1 = 1, i2 = 2, tmp;
  if (w[i0] < w[i1]) { tmp = i0; i0 = i1; i1 = tmp; }
  if (w[i0] < w[i2]) { tmp = i0; i0 = i2; i2 = tmp; }
  if (w[i1] < w[i2]) { tmp = i1; i1 = i2; i2 = tmp; }
  const double sv0 = sqrt(fmax(w[i0], 0.0));
  const double sv1 = sqrt(fmax(w[i1], 0.0));
  const double sv2 = sqrt(fmax(w[i2], 0.0));

  const double detK =
      K[0][0] * (K[1][1] * K[2][2] - K[1][2] * K[2][1]) -
      K[0][1] * (K[1][0] * K[2][2] - K[1][2] * K[2][0]) +
      K[0][2] * (K[1][0] * K[2][1] - K[1][1] * K[2][0]);
  const double sgn = (detK > 0.0) ? 1.0 : ((detK < 0.0) ? -1.0 : 0.0);

  const double floor0 = sv0 * 1e-12 + 1e-300;
  const double z0 = 1.0 / fmax(sv0, floor0);
  const double z1 = 1.0 / fmax(sv1, floor0);
  const double z2 = sgn / fmax(sv2, floor0);

  double W[3][3];
#pragma unroll
  for (int a = 0; a < 3; ++a)
#pragma unroll
    for (int c = 0; c < 3; ++c)
      W[a][c] = V[a][i0] * V[c][i0] * z0 + V[a][i1] * V[c][i1] * z1 +
                V[a][i2] * V[c][i2] * z2;

  double R[3][3];
#pragma unroll
  for (int a = 0; a < 3; ++a)
#pragma unroll
    for (int c = 0; c < 3; ++c)
      R[a][c] = W[a][0] * K[c][0] + W[a][1] * K[c][1] + W[a][2] * K[c][2];

  const double trace = sv0 + sv1 + sgn * sv2;
  const double scale = trace / var1;

  float* pr = params + b * 12;
#pragma unroll
  for (int a = 0; a < 3; ++a) {
#pragma unroll
    for (int c = 0; c < 3; ++c) pr[3 * a + c] = (float)(scale * R[a][c]);
    pr[9 + a] = (float)(mu2[a] - scale * (R[a][0] * mu1[0] + R[a][1] * mu1[1] +
                                          R[a][2] * mu1[2]));
  }
}

// ---------------------------------------------------------------------------
// Kernel 3: apply |M p + t - g| per point, float4-vectorized (4 pts/thread).
// ---------------------------------------------------------------------------
__device__ __forceinline__ void xform(const float* m, float p0, float p1,
                                      float p2, float g0, float g1, float g2,
                                      float& o0, float& o1, float& o2) {
  o0 = fabsf(m[0] * p0 + m[1] * p1 + m[2] * p2 + m[9] - g0);
  o1 = fabsf(m[3] * p0 + m[4] * p1 + m[5] * p2 + m[10] - g1);
  o2 = fabsf(m[6] * p0 + m[7] * p1 + m[8] * p2 + m[11] - g2);
}

__global__ __launch_bounds__(256) void apply_kernel(
    const float* __restrict__ pred, const float* __restrict__ gt,
    const float* __restrict__ params, float* __restrict__ out) {
  const int b = blockIdx.y;
  float m[12];
#pragma unroll
  for (int i = 0; i < 12; ++i) m[i] = params[b * 12 + i];  // uniform -> s_load

  const size_t ofs0 = (size_t)b * FLOATS_PER_BATCH;
  const int skip = (b & 1) ? 2 : 0;
  const size_t ofs = ofs0 + (size_t)skip * 3;
  const int gi = blockIdx.x * 256 + threadIdx.x;

  if (gi < NGROUPS) {
    const float4* __restrict__ p4 = (const float4*)(pred + ofs);
    const float4* __restrict__ g4 = (const float4*)(gt + ofs);
    float4* __restrict__ o4 = (float4*)(out + ofs);
    const float4 a0 = p4[3 * gi], a1 = p4[3 * gi + 1], a2 = p4[3 * gi + 2];
    const float4 c0 = g4[3 * gi], c1 = g4[3 * gi + 1], c2 = g4[3 * gi + 2];
    float4 r0, r1, r2;
    xform(m, a0.x, a0.y, a0.z, c0.x, c0.y, c0.z, r0.x, r0.y, r0.z);
    xform(m, a0.w, a1.x, a1.y, c0.w, c1.x, c1.y, r0.w, r1.x, r1.y);
    xform(m, a1.z, a1.w, a2.x, c1.z, c1.w, c2.x, r1.z, r1.w, r2.x);
    xform(m, a2.y, a2.z, a2.w, c2.y, c2.z, c2.w, r2.y, r2.z, r2.w);
    o4[3 * gi] = r0; o4[3 * gi + 1] = r1; o4[3 * gi + 2] = r2;
  }

  // 2 leftover scalar points per batch
  if (blockIdx.x == 0 && threadIdx.x < 2) {
    const int n = skip ? (int)threadIdx.x : (NPTS - 2 + (int)threadIdx.x);
    const float* pp = pred + ofs0 + 3 * n;
    const float* gg = gt + ofs0 + 3 * n;
    float* oo = out + ofs0 + 3 * n;
    xform(m, pp[0], pp[1], pp[2], gg[0], gg[1], gg[2], oo[0], oo[1], oo[2]);
  }
}

extern "C" void kernel_launch(void* const* d_in, const int* in_sizes, int n_in,
                              void* d_out, int out_size, void* d_ws, size_t ws_size,
                              hipStream_t stream) {
  const float* pred = (const float*)d_in[0];
  const float* gt   = (const float*)d_in[1];
  float* out = (float*)d_out;
  float* sums   = (float*)d_ws;            // BATCH*16 floats
  float* params = sums + BATCH * 16;       // BATCH*12 floats

  hipLaunchKernelGGL(reduce_kernel, dim3(BATCH), dim3(256), 0, stream,
                     pred, gt, sums);
  hipLaunchKernelGGL(solve_kernel, dim3((BATCH + 255) / 256), dim3(256), 0,
                     stream, sums, params);
  hipLaunchKernelGGL(apply_kernel, dim3((NGROUPS + 255) / 256, BATCH),
                     dim3(256), 0, stream, pred, gt, params, out);
}